// Round 1
// baseline (120.340 us; speedup 1.0000x reference)
//
#include <hip/hip_runtime.h>
#include <stdint.h>

#define D 128
#define MCOLS 196      // 14*14
#define XPITCH 232     // xc pitch (bf16); 116 dwords == 20 mod 32 -> 2-way (free)
#define BPITCH 136     // NS buffer pitch; 68 dwords == 4 mod 32 -> 2-way (free)
#define KOUT 8256      // 128*129/2

typedef short v8s __attribute__((ext_vector_type(8)));
typedef float v4f __attribute__((ext_vector_type(4)));

__device__ __forceinline__ uint32_t f2bf(float f) {
    uint32_t u = __builtin_bit_cast(uint32_t, f);
    u += 0x7FFFu + ((u >> 16) & 1u);   // RNE
    return u >> 16;
}
__device__ __forceinline__ float bf2f(uint32_t s) {
    uint32_t u = (s & 0xFFFFu) << 16;
    return __builtin_bit_cast(float, u);
}
__device__ __forceinline__ uint64_t pack4bf(float a, float b, float c, float d) {
    return (uint64_t)f2bf(a) | ((uint64_t)f2bf(b) << 16) |
           ((uint64_t)f2bf(c) << 32) | ((uint64_t)f2bf(d) << 48);
}

// One block per batch. 256 threads = 4 waves in a 2x2 wave grid; each wave owns a
// 64x64 output quadrant as 4x4 tiles of 16x16 MFMA.
// All NS matrices are symmetric (polynomials in A), so one row-major LDS copy
// serves both A-operand and B-operand reads (B[k][c] = Q[k][c] = Q[c][k] -> row read).
// Matrices carried as M = cM*I + R; cM exact compile-time scalar, R in bf16 LDS.
__global__ __launch_bounds__(256) void mpncov_kernel(const float* __restrict__ x,
                                                     float* __restrict__ out) {
    __shared__ __align__(16) uint16_t lds[3 * D * BPITCH];   // 104448 B
    __shared__ float psum[D][2];
    __shared__ float meanv[D];
    __shared__ float redbuf[4];

    uint16_t* const B0 = lds;
    uint16_t* const B1 = lds + D * BPITCH;
    uint16_t* const B2 = lds + 2 * D * BPITCH;
    // xc (128 x 232 bf16 = 59392 B) overlays B0+B1 (69632 B); dead before B0/B1 written
    uint16_t (*const xc)[XPITCH] = reinterpret_cast<uint16_t(*)[XPITCH]>(lds);

    const int tid = threadIdx.x;
    const int bb  = blockIdx.x;
    const float* __restrict__ xg = x + (size_t)bb * (D * MCOLS);

    // ---------- Phase 1a: load, row-sum, stash uncentered bf16; zero K-pad ----------
    {
        const int r = tid >> 1, h = tid & 1;
        const int c0  = h ? 25 : 0;
        const int cnt = h ? 24 : 25;                  // 49 float4 per row of 196
        const float4* row4 = reinterpret_cast<const float4*>(xg + r * MCOLS);
        float s = 0.f;
        for (int i = 0; i < cnt; ++i) {
            float4 v = row4[c0 + i];
            s += (v.x + v.y) + (v.z + v.w);
            *reinterpret_cast<uint64_t*>(&xc[r][(c0 + i) * 4]) = pack4bf(v.x, v.y, v.z, v.w);
        }
        psum[r][h] = s;
        for (int idx = tid; idx < D * 9; idx += 256) {        // zero cols 196..231
            int rr = idx / 9, q = idx - rr * 9;
            *reinterpret_cast<uint64_t*>(&xc[rr][MCOLS + q * 4]) = 0ull;
        }
    }
    __syncthreads();
    if (tid < D) meanv[tid] = (psum[tid][0] + psum[tid][1]) * (1.0f / MCOLS);
    __syncthreads();

    // ---------- Phase 1b: center in place (cols 0..199, predicated past 195) ----------
    for (int idx = tid; idx < D * 25; idx += 256) {
        const int r = idx / 25, ch = idx - r * 25;
        const int col = ch * 8;
        const float m = meanv[r];
        uint4 v = *reinterpret_cast<uint4*>(&xc[r][col]);
        uint32_t wds[4] = {v.x, v.y, v.z, v.w};
#pragma unroll
        for (int k = 0; k < 4; ++k) {
            const int cl = col + 2 * k;
            float lo = (cl     < MCOLS) ? bf2f(wds[k])       - m : 0.f;
            float hi = (cl + 1 < MCOLS) ? bf2f(wds[k] >> 16) - m : 0.f;
            wds[k] = f2bf(lo) | (f2bf(hi) << 16);
        }
        v.x = wds[0]; v.y = wds[1]; v.z = wds[2]; v.w = wds[3];
        *reinterpret_cast<uint4*>(&xc[r][col]) = v;
    }
    __syncthreads();

    // ---------- wave / lane geometry ----------
    const int lane = tid & 63;
    const int w  = tid >> 6;
    const int wr = w >> 1, wc = w & 1;
    const int lr = lane & 15, lk = lane >> 4;
    const int rA = 64 * wr + lr;   // A-frag row base (+16*i)
    const int rB = 64 * wc + lr;   // B-frag row base (+16*j)

    v4f acc[4][4];
#pragma unroll
    for (int i = 0; i < 4; ++i)
#pragma unroll
        for (int j = 0; j < 4; ++j) acc[i][j] = v4f{0.f, 0.f, 0.f, 0.f};

    // ---------- Phase 2: covraw = xc @ xc^T (K padded to 224) ----------
#pragma unroll
    for (int kk = 0; kk < 7; ++kk) {
        const int k0 = kk * 32 + lk * 8;
        v8s af[4], bf[4];
#pragma unroll
        for (int i = 0; i < 4; ++i) af[i] = *reinterpret_cast<const v8s*>(&xc[rA + 16 * i][k0]);
#pragma unroll
        for (int j = 0; j < 4; ++j) bf[j] = *reinterpret_cast<const v8s*>(&xc[rB + 16 * j][k0]);
#pragma unroll
        for (int i = 0; i < 4; ++i)
#pragma unroll
            for (int j = 0; j < 4; ++j)
                acc[i][j] = __builtin_amdgcn_mfma_f32_16x16x32_bf16(af[i], bf[j], acc[i][j], 0, 0, 0);
    }

    // trace(covraw): C/D layout col=lane&15, row=(lane>>4)*4+q  (m89-verified)
    float tval = 0.f;
    if (wr == wc && (lr >> 2) == lk) {
        const int q = lr & 3;
#pragma unroll
        for (int i = 0; i < 4; ++i) tval += acc[i][i][q];
    }
#pragma unroll
    for (int off = 32; off; off >>= 1) tval += __shfl_down(tval, off);
    if (lane == 0) redbuf[w] = tval;
    __syncthreads();
    const float tr  = (redbuf[0] + redbuf[1]) + (redbuf[2] + redbuf[3]);
    const float inv = 1.0f / tr;                       // A = covraw/tr (1/M cancels)
    const float outscale = sqrtf(tr * (1.0f / MCOLS)); // sqrt(trace(cov))

    // store residual from acc; symmetric -> store "transposed" form as contiguous b64
    auto store_res = [&](uint16_t* dst, float sc) {
#pragma unroll
        for (int i = 0; i < 4; ++i) {
            const int r0 = 64 * wr + 16 * i + 4 * lk;
#pragma unroll
            for (int j = 0; j < 4; ++j) {
                const int c = 64 * wc + 16 * j + lr;
                *reinterpret_cast<uint64_t*>(&dst[c * BPITCH + r0]) =
                    pack4bf(sc * acc[i][j][0], sc * acc[i][j][1],
                            sc * acc[i][j][2], sc * acc[i][j][3]);
            }
        }
    };

    // acc = RP@RQ + cP*RQ + cQ*RP   (residual of P@Q; identity part tracked statically)
    auto matmul = [&](const uint16_t* P, const uint16_t* Q, float cP, float cQ) {
#pragma unroll
        for (int i = 0; i < 4; ++i)
#pragma unroll
            for (int j = 0; j < 4; ++j) acc[i][j] = v4f{0.f, 0.f, 0.f, 0.f};
#pragma unroll
        for (int kk = 0; kk < 4; ++kk) {
            const int k0 = kk * 32 + lk * 8;
            v8s af[4], bf[4];
#pragma unroll
            for (int i = 0; i < 4; ++i)
                af[i] = *reinterpret_cast<const v8s*>(&P[(rA + 16 * i) * BPITCH + k0]);
#pragma unroll
            for (int j = 0; j < 4; ++j)
                bf[j] = *reinterpret_cast<const v8s*>(&Q[(rB + 16 * j) * BPITCH + k0]);
#pragma unroll
            for (int i = 0; i < 4; ++i)
#pragma unroll
                for (int j = 0; j < 4; ++j)
                    acc[i][j] = __builtin_amdgcn_mfma_f32_16x16x32_bf16(af[i], bf[j], acc[i][j], 0, 0, 0);
        }
        if (cQ != 0.f) {   // + cQ * RP[r][c]  (symmetric gather: RP[c][r0..r0+3])
#pragma unroll
            for (int i = 0; i < 4; ++i) {
                const int r0 = 64 * wr + 16 * i + 4 * lk;
#pragma unroll
                for (int j = 0; j < 4; ++j) {
                    const int c = 64 * wc + 16 * j + lr;
                    const uint64_t g = *reinterpret_cast<const uint64_t*>(&P[c * BPITCH + r0]);
                    acc[i][j][0] += cQ * bf2f((uint32_t)g);
                    acc[i][j][1] += cQ * bf2f((uint32_t)(g >> 16));
                    acc[i][j][2] += cQ * bf2f((uint32_t)(g >> 32));
                    acc[i][j][3] += cQ * bf2f((uint32_t)(g >> 48));
                }
            }
        }
        if (cP != 0.f) {   // + cP * RQ[r][c]
#pragma unroll
            for (int i = 0; i < 4; ++i) {
                const int r0 = 64 * wr + 16 * i + 4 * lk;
#pragma unroll
                for (int j = 0; j < 4; ++j) {
                    const int c = 64 * wc + 16 * j + lr;
                    const uint64_t g = *reinterpret_cast<const uint64_t*>(&Q[c * BPITCH + r0]);
                    acc[i][j][0] += cP * bf2f((uint32_t)g);
                    acc[i][j][1] += cP * bf2f((uint32_t)(g >> 16));
                    acc[i][j][2] += cP * bf2f((uint32_t)(g >> 32));
                    acc[i][j][3] += cP * bf2f((uint32_t)(g >> 48));
                }
            }
        }
    };

    // scalars: cA=0, cZY0=cZ1=1.5, cY*=0, cZY1=1.5, cZ2=2.25, cW=1.5 (all exact)
    store_res(B0, inv);           // RA   = covraw/tr          (A:   c=0)
    store_res(B1, -0.5f * inv);   // RZY0 = -0.5*RA            (ZY0: c=1.5)
    __syncthreads();

    matmul(B0, B1, 0.f, 1.5f);    // Y1 = A@ZY0 : RY1 = 1.5*RA + RA@RZY0
    __syncthreads();
    store_res(B2, 1.f);           // RY1 -> B2 (A dead)
    __syncthreads();

    matmul(B1, B2, 1.5f, 0.f);    // T1 = Z1@Y1 : RT1 = 1.5*RY1 + RZ1@RY1
    __syncthreads();
    store_res(B0, -0.5f);         // RZY1 = -0.5*RT1 -> B0     (ZY1: c=1.5)
    __syncthreads();

    matmul(B2, B0, 0.f, 1.5f);    // Y2 = Y1@ZY1 : RY2 = 1.5*RY1 + RY1@RZY1
    __syncthreads();
    store_res(B2, 1.f);           // RY2 -> B2 (Y1 dead)
    __syncthreads();

    matmul(B0, B1, 1.5f, 1.5f);   // Z2 = ZY1@Z1 : RZ2 = 1.5*RZ1 + 1.5*RZY1 + RZY1@RZ1
    __syncthreads();
    store_res(B1, 1.f);           // RZ2 -> B1 (Z1 dead)       (Z2: c=2.25)
    __syncthreads();

    matmul(B1, B2, 2.25f, 0.f);   // T2 = Z2@Y2 : RT2 = 2.25*RY2 + RZ2@RY2
    __syncthreads();
    store_res(B0, -0.5f);         // RW = -0.5*RT2 -> B0       (W: c=1.5)
    __syncthreads();

    // ---------- MM6: O = Y2@W = 1.5*RY2 + RY2@RW (c=0); scale + triu store ----------
    // wave 2 (rows 64..127, cols 0..63) is entirely below the diagonal: skip.
    if (w != 2) {
        const bool diagw = (wr == wc);
#pragma unroll
        for (int i = 0; i < 4; ++i)
#pragma unroll
            for (int j = 0; j < 4; ++j) acc[i][j] = v4f{0.f, 0.f, 0.f, 0.f};
#pragma unroll
        for (int kk = 0; kk < 4; ++kk) {
            const int k0 = kk * 32 + lk * 8;
            v8s af[4], bf[4];
#pragma unroll
            for (int i = 0; i < 4; ++i)
                af[i] = *reinterpret_cast<const v8s*>(&B2[(rA + 16 * i) * BPITCH + k0]);
#pragma unroll
            for (int j = 0; j < 4; ++j)
                bf[j] = *reinterpret_cast<const v8s*>(&B0[(rB + 16 * j) * BPITCH + k0]);
#pragma unroll
            for (int i = 0; i < 4; ++i)
#pragma unroll
                for (int j = 0; j < 4; ++j)
                    if (!diagw || i <= j)
                        acc[i][j] = __builtin_amdgcn_mfma_f32_16x16x32_bf16(af[i], bf[j], acc[i][j], 0, 0, 0);
        }
        float* ob = out + (size_t)bb * KOUT;
#pragma unroll
        for (int i = 0; i < 4; ++i) {
            const int r0 = 64 * wr + 16 * i + 4 * lk;
#pragma unroll
            for (int j = 0; j < 4; ++j) {
                if (diagw && i > j) continue;
                const int c = 64 * wc + 16 * j + lr;
                const uint64_t g = *reinterpret_cast<const uint64_t*>(&B2[c * BPITCH + r0]);
                float vv[4];
                vv[0] = (acc[i][j][0] + 1.5f * bf2f((uint32_t)g))         * outscale;
                vv[1] = (acc[i][j][1] + 1.5f * bf2f((uint32_t)(g >> 16))) * outscale;
                vv[2] = (acc[i][j][2] + 1.5f * bf2f((uint32_t)(g >> 32))) * outscale;
                vv[3] = (acc[i][j][3] + 1.5f * bf2f((uint32_t)(g >> 48))) * outscale;
#pragma unroll
                for (int q = 0; q < 4; ++q) {
                    const int r = r0 + q;
                    if (r <= c) ob[r * D - (r * (r + 1)) / 2 + c] = vv[q];
                }
            }
        }
    }
}

extern "C" void kernel_launch(void* const* d_in, const int* in_sizes, int n_in,
                              void* d_out, int out_size, void* d_ws, size_t ws_size,
                              hipStream_t stream) {
    const float* x = (const float*)d_in[0];
    float* out = (float*)d_out;
    mpncov_kernel<<<dim3(1024), dim3(256), 0, stream>>>(x, out);
}

// Round 2
// 91.597 us; speedup vs baseline: 1.3138x; 1.3138x over previous
//
#include <hip/hip_runtime.h>
#include <stdint.h>

#define D 128
#define MCOLS 196      // 14*14
#define XPITCH 232     // xc pitch (bf16); 116 dwords == 20 mod 32 -> 2-way (free)
#define BPITCH 136     // NS buffer pitch; 68 dwords == 4 mod 32 -> 2-way (free)
#define KOUT 8256      // 128*129/2

typedef short v8s __attribute__((ext_vector_type(8)));
typedef float v4f __attribute__((ext_vector_type(4)));

__device__ __forceinline__ uint32_t f2bf(float f) {
    uint32_t u = __builtin_bit_cast(uint32_t, f);
    u += 0x7FFFu + ((u >> 16) & 1u);   // RNE
    return u >> 16;
}
__device__ __forceinline__ float bf2f(uint32_t s) {
    uint32_t u = (s & 0xFFFFu) << 16;
    return __builtin_bit_cast(float, u);
}
__device__ __forceinline__ uint64_t pack4bf(float a, float b, float c, float d) {
    return (uint64_t)f2bf(a) | ((uint64_t)f2bf(b) << 16) |
           ((uint64_t)f2bf(c) << 32) | ((uint64_t)f2bf(d) << 48);
}

// One block per batch, 512 threads = 8 waves in a 2x4 wave grid; each wave owns a
// 64x32 output region as 4x2 tiles of 16x16 MFMA.
// All NS matrices are symmetric (polynomials in A) -> one row-major LDS copy
// serves both MFMA operands. Matrices carried as M = cM*I + R (cM exact scalar,
// R bf16 in LDS). 4 LDS buffers => each stage writes a dead non-operand buffer
// => single barrier per stage.
__global__ __launch_bounds__(512) void mpncov_kernel(const float* __restrict__ x,
                                                     float* __restrict__ out) {
    __shared__ __align__(16) uint16_t lds[4 * D * BPITCH];   // 139264 B
    __shared__ float psum[D][4];
    __shared__ float meanv[D];
    __shared__ float redbuf[8];

    uint16_t* const B0 = lds;
    uint16_t* const B1 = lds + 1 * D * BPITCH;
    uint16_t* const B2 = lds + 2 * D * BPITCH;
    uint16_t* const B3 = lds + 3 * D * BPITCH;
    // xc (128 x 232 bf16 = 59392 B) overlays B0+B1 (69632 B); dead before B0/B1 written
    uint16_t (*const xc)[XPITCH] = reinterpret_cast<uint16_t(*)[XPITCH]>(lds);

    const int tid = threadIdx.x;
    const int bb  = blockIdx.x;
    const float* __restrict__ xg = x + (size_t)bb * (D * MCOLS);

    // ---------- Phase 1a: load, row-sum, stash uncentered bf16; zero K-pad ----------
    {
        const int r = tid >> 2, q = tid & 3;
        const int c0  = q * 12;
        const int cnt = (q == 3) ? 13 : 12;           // 49 float4 per row of 196
        const float4* row4 = reinterpret_cast<const float4*>(xg + r * MCOLS);
        float s = 0.f;
        for (int i = 0; i < cnt; ++i) {
            float4 v = row4[c0 + i];
            s += (v.x + v.y) + (v.z + v.w);
            *reinterpret_cast<uint64_t*>(&xc[r][(c0 + i) * 4]) = pack4bf(v.x, v.y, v.z, v.w);
        }
        psum[r][q] = s;
        for (int idx = tid; idx < D * 9; idx += 512) {        // zero cols 196..231
            int rr = idx / 9, p = idx - rr * 9;
            *reinterpret_cast<uint64_t*>(&xc[rr][MCOLS + p * 4]) = 0ull;
        }
    }
    __syncthreads();
    if (tid < D) meanv[tid] = (psum[tid][0] + psum[tid][1] + psum[tid][2] + psum[tid][3]) * (1.0f / MCOLS);
    __syncthreads();

    // ---------- Phase 1b: center in place (cols 0..199, predicated past 195) ----------
    for (int idx = tid; idx < D * 25; idx += 512) {
        const int r = idx / 25, ch = idx - r * 25;
        const int col = ch * 8;
        const float m = meanv[r];
        uint4 v = *reinterpret_cast<uint4*>(&xc[r][col]);
        uint32_t wds[4] = {v.x, v.y, v.z, v.w};
#pragma unroll
        for (int k = 0; k < 4; ++k) {
            const int cl = col + 2 * k;
            float lo = (cl     < MCOLS) ? bf2f(wds[k])       - m : 0.f;
            float hi = (cl + 1 < MCOLS) ? bf2f(wds[k] >> 16) - m : 0.f;
            wds[k] = f2bf(lo) | (f2bf(hi) << 16);
        }
        v.x = wds[0]; v.y = wds[1]; v.z = wds[2]; v.w = wds[3];
        *reinterpret_cast<uint4*>(&xc[r][col]) = v;
    }
    __syncthreads();

    // ---------- wave / lane geometry (2x4 wave grid) ----------
    const int lane = tid & 63;
    const int w  = tid >> 6;        // 0..7
    const int wr = w >> 2;          // 0..1 : rows 64*wr
    const int wc = w & 3;           // 0..3 : cols 32*wc
    const int lr = lane & 15, lk = lane >> 4;
    const int rA = 64 * wr + lr;    // A-frag row base (+16*i)
    const int rB = 32 * wc + lr;    // B-frag row base (+16*j)

    v4f acc[4][2];
#pragma unroll
    for (int i = 0; i < 4; ++i)
#pragma unroll
        for (int j = 0; j < 2; ++j) acc[i][j] = v4f{0.f, 0.f, 0.f, 0.f};

    // ---------- Phase 2: covraw = xc @ xc^T (K padded to 224) ----------
#pragma unroll
    for (int kk = 0; kk < 7; ++kk) {
        const int k0 = kk * 32 + lk * 8;
        v8s af[4], bf[2];
#pragma unroll
        for (int i = 0; i < 4; ++i) af[i] = *reinterpret_cast<const v8s*>(&xc[rA + 16 * i][k0]);
#pragma unroll
        for (int j = 0; j < 2; ++j) bf[j] = *reinterpret_cast<const v8s*>(&xc[rB + 16 * j][k0]);
#pragma unroll
        for (int i = 0; i < 4; ++i)
#pragma unroll
            for (int j = 0; j < 2; ++j)
                acc[i][j] = __builtin_amdgcn_mfma_f32_16x16x32_bf16(af[i], bf[j], acc[i][j], 0, 0, 0);
    }

    // trace(covraw): C/D layout col=lane&15, row=(lane>>4)*4+q  (m89-verified)
    float tval = 0.f;
    if ((lr >> 2) == lk) {
        const int q = lr & 3;
#pragma unroll
        for (int i = 0; i < 4; ++i)
#pragma unroll
            for (int j = 0; j < 2; ++j)
                if (4 * wr + i == 2 * wc + j) tval += acc[i][j][q];
    }
#pragma unroll
    for (int off = 32; off; off >>= 1) tval += __shfl_down(tval, off);
    if (lane == 0) redbuf[w] = tval;
    __syncthreads();
    const float tr  = ((redbuf[0] + redbuf[1]) + (redbuf[2] + redbuf[3])) +
                      ((redbuf[4] + redbuf[5]) + (redbuf[6] + redbuf[7]));
    const float inv = 1.0f / tr;                       // A = covraw/tr (1/M cancels)
    const float outscale = sqrtf(tr * (1.0f / MCOLS)); // sqrt(trace(cov))

    // store residual from acc; symmetric -> store "transposed" form as contiguous b64
    auto store_res = [&](uint16_t* dst, float sc) {
#pragma unroll
        for (int i = 0; i < 4; ++i) {
            const int r0 = 64 * wr + 16 * i + 4 * lk;
#pragma unroll
            for (int j = 0; j < 2; ++j) {
                const int c = 32 * wc + 16 * j + lr;
                *reinterpret_cast<uint64_t*>(&dst[c * BPITCH + r0]) =
                    pack4bf(sc * acc[i][j][0], sc * acc[i][j][1],
                            sc * acc[i][j][2], sc * acc[i][j][3]);
            }
        }
    };

    // acc = RP@RQ + cP*RQ + cQ*RP   (residual of P@Q; identity part tracked statically)
    auto matmul = [&](const uint16_t* P, const uint16_t* Q, float cP, float cQ) {
#pragma unroll
        for (int i = 0; i < 4; ++i)
#pragma unroll
            for (int j = 0; j < 2; ++j) acc[i][j] = v4f{0.f, 0.f, 0.f, 0.f};
#pragma unroll
        for (int kk = 0; kk < 4; ++kk) {
            const int k0 = kk * 32 + lk * 8;
            v8s af[4], bf[2];
#pragma unroll
            for (int i = 0; i < 4; ++i)
                af[i] = *reinterpret_cast<const v8s*>(&P[(rA + 16 * i) * BPITCH + k0]);
#pragma unroll
            for (int j = 0; j < 2; ++j)
                bf[j] = *reinterpret_cast<const v8s*>(&Q[(rB + 16 * j) * BPITCH + k0]);
#pragma unroll
            for (int i = 0; i < 4; ++i)
#pragma unroll
                for (int j = 0; j < 2; ++j)
                    acc[i][j] = __builtin_amdgcn_mfma_f32_16x16x32_bf16(af[i], bf[j], acc[i][j], 0, 0, 0);
        }
        if (cQ != 0.f) {   // + cQ * RP[r][c]  (symmetric gather: RP[c][r0..r0+3])
#pragma unroll
            for (int i = 0; i < 4; ++i) {
                const int r0 = 64 * wr + 16 * i + 4 * lk;
#pragma unroll
                for (int j = 0; j < 2; ++j) {
                    const int c = 32 * wc + 16 * j + lr;
                    const uint64_t g = *reinterpret_cast<const uint64_t*>(&P[c * BPITCH + r0]);
                    acc[i][j][0] += cQ * bf2f((uint32_t)g);
                    acc[i][j][1] += cQ * bf2f((uint32_t)(g >> 16));
                    acc[i][j][2] += cQ * bf2f((uint32_t)(g >> 32));
                    acc[i][j][3] += cQ * bf2f((uint32_t)(g >> 48));
                }
            }
        }
        if (cP != 0.f) {   // + cP * RQ[r][c]
#pragma unroll
            for (int i = 0; i < 4; ++i) {
                const int r0 = 64 * wr + 16 * i + 4 * lk;
#pragma unroll
                for (int j = 0; j < 2; ++j) {
                    const int c = 32 * wc + 16 * j + lr;
                    const uint64_t g = *reinterpret_cast<const uint64_t*>(&Q[c * BPITCH + r0]);
                    acc[i][j][0] += cP * bf2f((uint32_t)g);
                    acc[i][j][1] += cP * bf2f((uint32_t)(g >> 16));
                    acc[i][j][2] += cP * bf2f((uint32_t)(g >> 32));
                    acc[i][j][3] += cP * bf2f((uint32_t)(g >> 48));
                }
            }
        }
    };

    // Buffer rotation (each stage writes a dead, non-operand buffer -> 1 barrier/stage):
    //   B0=RA, B1=RZY0 -> MM1(B0,B1)->B2=RY1 -> MM2(B1,B2)->B3=RZY1 ->
    //   MM3(B2,B3)->B0=RY2 -> MM4(B3,B1)->B2=RZ2 -> MM5(B2,B0)->B1=RW -> MM6(B0,B1)->out
    // scalars: cA=0, cZY0=cZ1=1.5, cY*=0, cZY1=1.5, cZ2=2.25, cW=1.5 (all exact)
    store_res(B0, inv);           // RA   = covraw/tr          (A:   c=0)
    store_res(B1, -0.5f * inv);   // RZY0 = -0.5*RA            (ZY0: c=1.5)
    __syncthreads();

    matmul(B0, B1, 0.f, 1.5f);    // Y1 = A@ZY0 : RY1 = 1.5*RA + RA@RZY0
    store_res(B2, 1.f);
    __syncthreads();

    matmul(B1, B2, 1.5f, 0.f);    // T1 = Z1@Y1 : RT1 = 1.5*RY1 + RZ1@RY1
    store_res(B3, -0.5f);         // RZY1 = -0.5*RT1           (ZY1: c=1.5)
    __syncthreads();

    matmul(B2, B3, 0.f, 1.5f);    // Y2 = Y1@ZY1 : RY2 = 1.5*RY1 + RY1@RZY1
    store_res(B0, 1.f);
    __syncthreads();

    matmul(B3, B1, 1.5f, 1.5f);   // Z2 = ZY1@Z1 : RZ2 = 1.5*RZ1 + 1.5*RZY1 + RZY1@RZ1
    store_res(B2, 1.f);           //                           (Z2: c=2.25)
    __syncthreads();

    matmul(B2, B0, 2.25f, 0.f);   // T2 = Z2@Y2 : RT2 = 2.25*RY2 + RZ2@RY2
    store_res(B1, -0.5f);         // RW = -0.5*RT2             (W: c=1.5)
    __syncthreads();

    // ---------- MM6: O = Y2@W = 1.5*RY2 + RY2@RW (c=0); scale + triu store ----------
    // waves (wr=1, wc<2) are entirely below the diagonal: skip.
    if (!(wr == 1 && wc < 2)) {
#pragma unroll
        for (int i = 0; i < 4; ++i)
#pragma unroll
            for (int j = 0; j < 2; ++j) acc[i][j] = v4f{0.f, 0.f, 0.f, 0.f};
#pragma unroll
        for (int kk = 0; kk < 4; ++kk) {
            const int k0 = kk * 32 + lk * 8;
            v8s af[4], bf[2];
#pragma unroll
            for (int i = 0; i < 4; ++i)
                af[i] = *reinterpret_cast<const v8s*>(&B0[(rA + 16 * i) * BPITCH + k0]);
#pragma unroll
            for (int j = 0; j < 2; ++j)
                bf[j] = *reinterpret_cast<const v8s*>(&B1[(rB + 16 * j) * BPITCH + k0]);
#pragma unroll
            for (int i = 0; i < 4; ++i)
#pragma unroll
                for (int j = 0; j < 2; ++j)
                    if (4 * wr + i <= 2 * wc + j)   // skip tiles fully below diagonal
                        acc[i][j] = __builtin_amdgcn_mfma_f32_16x16x32_bf16(af[i], bf[j], acc[i][j], 0, 0, 0);
        }
        float* ob = out + (size_t)bb * KOUT;
#pragma unroll
        for (int i = 0; i < 4; ++i) {
            const int r0 = 64 * wr + 16 * i + 4 * lk;
#pragma unroll
            for (int j = 0; j < 2; ++j) {
                const int rb = 4 * wr + i, cbk = 2 * wc + j;
                if (rb > cbk) continue;
                const int c = 32 * wc + 16 * j + lr;
                const uint64_t g = *reinterpret_cast<const uint64_t*>(&B0[c * BPITCH + r0]);
                float vv[4];
                vv[0] = (acc[i][j][0] + 1.5f * bf2f((uint32_t)g))         * outscale;
                vv[1] = (acc[i][j][1] + 1.5f * bf2f((uint32_t)(g >> 16))) * outscale;
                vv[2] = (acc[i][j][2] + 1.5f * bf2f((uint32_t)(g >> 32))) * outscale;
                vv[3] = (acc[i][j][3] + 1.5f * bf2f((uint32_t)(g >> 48))) * outscale;
                if (rb < cbk) {
#pragma unroll
                    for (int q = 0; q < 4; ++q) {
                        const int r = r0 + q;
                        ob[r * D - (r * (r + 1)) / 2 + c] = vv[q];
                    }
                } else {
#pragma unroll
                    for (int q = 0; q < 4; ++q) {
                        const int r = r0 + q;
                        if (r <= c) ob[r * D - (r * (r + 1)) / 2 + c] = vv[q];
                    }
                }
            }
        }
    }
}

extern "C" void kernel_launch(void* const* d_in, const int* in_sizes, int n_in,
                              void* d_out, int out_size, void* d_ws, size_t ws_size,
                              hipStream_t stream) {
    const float* x = (const float*)d_in[0];
    float* out = (float*)d_out;
    mpncov_kernel<<<dim3(1024), dim3(512), 0, stream>>>(x, out);
}

// Round 3
// 71.479 us; speedup vs baseline: 1.6836x; 1.2815x over previous
//
#include <hip/hip_runtime.h>
#include <stdint.h>

#define D 128
#define MCOLS 196      // 14*14
#define XPITCH 232     // xc pitch (bf16); 116 dwords == 20 mod 32 -> 2-way (free)
#define BPITCH 136     // NS buffer pitch; 68 dwords == 4 mod 32 -> 2-way (free)
#define KOUT 8256      // 128*129/2

typedef short v8s __attribute__((ext_vector_type(8)));
typedef float v4f __attribute__((ext_vector_type(4)));

__device__ __forceinline__ uint32_t f2bf(float f) {
    uint32_t u = __builtin_bit_cast(uint32_t, f);
    u += 0x7FFFu + ((u >> 16) & 1u);   // RNE
    return u >> 16;
}
__device__ __forceinline__ float bf2f(uint32_t s) {
    uint32_t u = (s & 0xFFFFu) << 16;
    return __builtin_bit_cast(float, u);
}
__device__ __forceinline__ uint64_t pack4bf(float a, float b, float c, float d) {
    return (uint64_t)f2bf(a) | ((uint64_t)f2bf(b) << 16) |
           ((uint64_t)f2bf(c) << 32) | ((uint64_t)f2bf(d) << 48);
}

// One block per batch, 1024 threads = 16 waves in a 4x4 wave grid; each wave owns a
// 32x32 output region as 2x2 tiles of 16x16 MFMA (4 waves/SIMD for latency hiding).
// All NS matrices are symmetric & commute (polynomials of A) -> one row-major LDS
// copy serves both MFMA operands. Matrices carried as M = cM*I + R (cM exact
// compile-time scalar, R bf16 in LDS). Linear terms cP*RQ + cQ*RP are over the
// wave's OWN region -> taken from per-wave f32 REGISTER copies (no LDS gather).
__global__ __launch_bounds__(1024) void mpncov_kernel(const float* __restrict__ x,
                                                      float* __restrict__ out) {
    __shared__ __align__(16) uint16_t lds[4 * D * BPITCH];   // 139264 B
    __shared__ float redbuf[16];

    uint16_t* const B0 = lds;
    uint16_t* const B1 = lds + 1 * D * BPITCH;
    uint16_t* const B2 = lds + 2 * D * BPITCH;
    uint16_t* const B3 = lds + 3 * D * BPITCH;
    // xc (128 x 232 bf16 = 59392 B) overlays B0+B1; dead before B0/B1 written
    uint16_t (*const xc)[XPITCH] = reinterpret_cast<uint16_t(*)[XPITCH]>(lds);

    const int tid = threadIdx.x;
    const int bb  = blockIdx.x;
    const float* __restrict__ xg = x + (size_t)bb * (D * MCOLS);

    // ---------- Phase 1: load, mean via 8-lane shfl, center in regs, write bf16 ----------
    {
        const int r = tid >> 3, q = tid & 7;          // 8 threads per row
        const float4* row4 = reinterpret_cast<const float4*>(xg + r * MCOLS);
        float4 v[6]; float4 vx{0.f, 0.f, 0.f, 0.f};
        float s = 0.f;
#pragma unroll
        for (int i = 0; i < 6; ++i) {                 // chunks q+8i, i=0..5 (48 of 49)
            v[i] = row4[8 * i + q];
            s += (v[i].x + v[i].y) + (v[i].z + v[i].w);
        }
        if (q == 0) {                                 // chunk 48 (cols 192..195)
            vx = row4[48];
            s += (vx.x + vx.y) + (vx.z + vx.w);
        }
        s += __shfl_xor(s, 1); s += __shfl_xor(s, 2); s += __shfl_xor(s, 4);
        const float m = s * (1.0f / MCOLS);
#pragma unroll
        for (int i = 0; i < 6; ++i)
            *reinterpret_cast<uint64_t*>(&xc[r][(8 * i + q) * 4]) =
                pack4bf(v[i].x - m, v[i].y - m, v[i].z - m, v[i].w - m);
        if (q == 0)
            *reinterpret_cast<uint64_t*>(&xc[r][192]) =
                pack4bf(vx.x - m, vx.y - m, vx.z - m, vx.w - m);
        if (tid < D * 7) {                            // zero K-pad cols 196..223
            const int rr = tid / 7, p = tid - rr * 7;
            *reinterpret_cast<uint64_t*>(&xc[rr][MCOLS + 4 * p]) = 0ull;
        }
    }
    __syncthreads();                                  // A

    // ---------- wave / lane geometry (4x4 wave grid, 2x2 tiles per wave) ----------
    const int lane = tid & 63;
    const int w  = tid >> 6;        // 0..15
    const int wr = w >> 2;          // 0..3 : rows 32*wr
    const int wc = w & 3;           // 0..3 : cols 32*wc
    const int lr = lane & 15, lk = lane >> 4;

    v4f acc[2][2];
#pragma unroll
    for (int i = 0; i < 2; ++i)
#pragma unroll
        for (int j = 0; j < 2; ++j) acc[i][j] = v4f{0.f, 0.f, 0.f, 0.f};

    // ---------- cov: covraw = xc @ xc^T (K padded to 224) ----------
#pragma unroll
    for (int kk = 0; kk < 7; ++kk) {
        const int k0 = kk * 32 + lk * 8;
        v8s af[2], bf[2];
#pragma unroll
        for (int i = 0; i < 2; ++i)
            af[i] = *reinterpret_cast<const v8s*>(&xc[32 * wr + 16 * i + lr][k0]);
#pragma unroll
        for (int j = 0; j < 2; ++j)
            bf[j] = *reinterpret_cast<const v8s*>(&xc[32 * wc + 16 * j + lr][k0]);
#pragma unroll
        for (int i = 0; i < 2; ++i)
#pragma unroll
            for (int j = 0; j < 2; ++j)
                acc[i][j] = __builtin_amdgcn_mfma_f32_16x16x32_bf16(af[i], bf[j], acc[i][j], 0, 0, 0);
    }

    // trace(covraw): C/D layout col=lane&15, row=(lane>>4)*4+q (m89-verified)
    float tval = 0.f;
    if (wr == wc && (lr >> 2) == lk) {
        const int qq = lr & 3;
        tval = acc[0][0][qq] + acc[1][1][qq];
    }
#pragma unroll
    for (int off = 32; off; off >>= 1) tval += __shfl_down(tval, off);
    if (lane == 0) redbuf[w] = tval;
    __syncthreads();                                  // B (also covers xc-read vs B0-write)
    float tr = 0.f;
#pragma unroll
    for (int t = 0; t < 16; ++t) tr += redbuf[t];
    const float inv = 1.0f / tr;                       // A = covraw/tr (1/M cancels)
    const float outscale = sqrtf(tr * (1.0f / MCOLS)); // sqrt(trace(cov))

    // store wave's 2x2 region transposed (symmetry) as contiguous b64
    auto store2 = [&](uint16_t* dst, const v4f (&mm)[2][2]) {
#pragma unroll
        for (int i = 0; i < 2; ++i) {
            const int r0 = 32 * wr + 16 * i + 4 * lk;
#pragma unroll
            for (int j = 0; j < 2; ++j) {
                const int c = 32 * wc + 16 * j + lr;
                *reinterpret_cast<uint64_t*>(&dst[c * BPITCH + r0]) =
                    pack4bf(mm[i][j][0], mm[i][j][1], mm[i][j][2], mm[i][j][3]);
            }
        }
    };
    // acc = RP @ RQ (residual product only; both operands row-read, symmetric)
    auto matmul = [&](const uint16_t* P, const uint16_t* Q) {
#pragma unroll
        for (int i = 0; i < 2; ++i)
#pragma unroll
            for (int j = 0; j < 2; ++j) acc[i][j] = v4f{0.f, 0.f, 0.f, 0.f};
#pragma unroll
        for (int kk = 0; kk < 4; ++kk) {
            const int k0 = kk * 32 + lk * 8;
            v8s af[2], bf[2];
#pragma unroll
            for (int i = 0; i < 2; ++i)
                af[i] = *reinterpret_cast<const v8s*>(&P[(32 * wr + 16 * i + lr) * BPITCH + k0]);
#pragma unroll
            for (int j = 0; j < 2; ++j)
                bf[j] = *reinterpret_cast<const v8s*>(&Q[(32 * wc + 16 * j + lr) * BPITCH + k0]);
#pragma unroll
            for (int i = 0; i < 2; ++i)
#pragma unroll
                for (int j = 0; j < 2; ++j)
                    acc[i][j] = __builtin_amdgcn_mfma_f32_16x16x32_bf16(af[i], bf[j], acc[i][j], 0, 0, 0);
        }
    };

    // register copies of this wave's own region (f32) for linear terms
    v4f regA[2][2], regY1[2][2], regZY1[2][2], regY2[2][2];

#pragma unroll
    for (int i = 0; i < 2; ++i)
#pragma unroll
        for (int j = 0; j < 2; ++j)
#pragma unroll
            for (int q = 0; q < 4; ++q) regA[i][j][q] = acc[i][j][q] * inv;
    store2(B0, regA);                                  // RA -> B0
    __syncthreads();                                  // C

    // MM1: Y1 = A@ZY0, ZY0 = 1.5I - 0.5A  => RY1 = -0.5*(RA@RA) + 1.5*RA
    matmul(B0, B0);
#pragma unroll
    for (int i = 0; i < 2; ++i)
#pragma unroll
        for (int j = 0; j < 2; ++j)
#pragma unroll
            for (int q = 0; q < 4; ++q)
                regY1[i][j][q] = -0.5f * acc[i][j][q] + 1.5f * regA[i][j][q];
    store2(B1, regY1);                                 // RY1 -> B1
    __syncthreads();                                  // D

    // MM2: T1 = Z1@Y1, Z1 = 1.5I - 0.5A => RT1 = -0.5*(RA@RY1) + 1.5*RY1
    //      RZY1 = -0.5*RT1 = 0.25*(RA@RY1) - 0.75*RY1
    matmul(B0, B1);
#pragma unroll
    for (int i = 0; i < 2; ++i)
#pragma unroll
        for (int j = 0; j < 2; ++j)
#pragma unroll
            for (int q = 0; q < 4; ++q)
                regZY1[i][j][q] = 0.25f * acc[i][j][q] - 0.75f * regY1[i][j][q];
    store2(B2, regZY1);                                // RZY1 -> B2
    __syncthreads();                                  // E

    // MM3: Y2 = Y1@ZY1 => RY2 = RY1@RZY1 + 1.5*RY1   (cY1=0, cZY1=1.5)
    matmul(B1, B2);
#pragma unroll
    for (int i = 0; i < 2; ++i)
#pragma unroll
        for (int j = 0; j < 2; ++j)
#pragma unroll
            for (int q = 0; q < 4; ++q)
                regY2[i][j][q] = acc[i][j][q] + 1.5f * regY1[i][j][q];
    store2(B3, regY2);                                 // RY2 -> B3
    __syncthreads();                                  // F

    // MM4: Z2 = ZY1@Z1 => RZ2 = -0.5*(RZY1@RA) - 0.75*RA + 1.5*RZY1
    matmul(B2, B0);
#pragma unroll
    for (int i = 0; i < 2; ++i)
#pragma unroll
        for (int j = 0; j < 2; ++j)
#pragma unroll
            for (int q = 0; q < 4; ++q)
                acc[i][j][q] = -0.5f * acc[i][j][q] - 0.75f * regA[i][j][q] + 1.5f * regZY1[i][j][q];
    {
        v4f (&regZ2)[2][2] = regA;                     // regA dead: reuse as staging
#pragma unroll
        for (int i = 0; i < 2; ++i)
#pragma unroll
            for (int j = 0; j < 2; ++j) regZ2[i][j] = acc[i][j];
        store2(B1, regZ2);                             // RZ2 -> B1 (RY1 dead)
    }
    __syncthreads();                                  // G

    // MM5: T2 = Z2@Y2 => RT2 = RZ2@RY2 + 2.25*RY2    (cZ2=2.25, cY2=0)
    matmul(B1, B3);
#pragma unroll
    for (int i = 0; i < 2; ++i)
#pragma unroll
        for (int j = 0; j < 2; ++j)
#pragma unroll
            for (int q = 0; q < 4; ++q)
                acc[i][j][q] = acc[i][j][q] + 2.25f * regY2[i][j][q];
    {
        v4f (&regT2)[2][2] = regZY1;                   // regZY1 dead: reuse
#pragma unroll
        for (int i = 0; i < 2; ++i)
#pragma unroll
            for (int j = 0; j < 2; ++j) regT2[i][j] = acc[i][j];
        store2(B2, regT2);                             // RT2 -> B2 (RZY1 dead)
    }
    __syncthreads();                                  // H

    // ---------- MM6: O = Y2@W, W = 1.5I - 0.5*T2 => O = 1.5*RY2 - 0.5*(RY2@RT2) ----------
    if (wr <= wc) {
#pragma unroll
        for (int i = 0; i < 2; ++i)
#pragma unroll
            for (int j = 0; j < 2; ++j) acc[i][j] = v4f{0.f, 0.f, 0.f, 0.f};
#pragma unroll
        for (int kk = 0; kk < 4; ++kk) {
            const int k0 = kk * 32 + lk * 8;
            v8s af[2], bf[2];
#pragma unroll
            for (int i = 0; i < 2; ++i)
                af[i] = *reinterpret_cast<const v8s*>(&B3[(32 * wr + 16 * i + lr) * BPITCH + k0]);
#pragma unroll
            for (int j = 0; j < 2; ++j)
                bf[j] = *reinterpret_cast<const v8s*>(&B2[(32 * wc + 16 * j + lr) * BPITCH + k0]);
#pragma unroll
            for (int i = 0; i < 2; ++i)
#pragma unroll
                for (int j = 0; j < 2; ++j)
                    if (2 * wr + i <= 2 * wc + j)
                        acc[i][j] = __builtin_amdgcn_mfma_f32_16x16x32_bf16(af[i], bf[j], acc[i][j], 0, 0, 0);
        }
        float* ob = out + (size_t)bb * KOUT;
#pragma unroll
        for (int i = 0; i < 2; ++i) {
            const int r0 = 32 * wr + 16 * i + 4 * lk;
#pragma unroll
            for (int j = 0; j < 2; ++j) {
                const int rb = 2 * wr + i, cb = 2 * wc + j;
                if (rb > cb) continue;
                const int c = 32 * wc + 16 * j + lr;
                float vv[4];
#pragma unroll
                for (int q = 0; q < 4; ++q)
                    vv[q] = (1.5f * regY2[i][j][q] - 0.5f * acc[i][j][q]) * outscale;
                if (rb < cb) {
#pragma unroll
                    for (int q = 0; q < 4; ++q) {
                        const int r = r0 + q;
                        ob[r * D - (r * (r + 1)) / 2 + c] = vv[q];
                    }
                } else {
#pragma unroll
                    for (int q = 0; q < 4; ++q) {
                        const int r = r0 + q;
                        if (r <= c) ob[r * D - (r * (r + 1)) / 2 + c] = vv[q];
                    }
                }
            }
        }
    }
}

extern "C" void kernel_launch(void* const* d_in, const int* in_sizes, int n_in,
                              void* d_out, int out_size, void* d_ws, size_t ws_size,
                              hipStream_t stream) {
    const float* x = (const float*)d_in[0];
    float* out = (float*)d_out;
    mpncov_kernel<<<dim3(1024), dim3(1024), 0, stream>>>(x, out);
}